// Round 10
// baseline (405.543 us; speedup 1.0000x reference)
//
#include <hip/hip_runtime.h>

#define NTAG 64
#define SOS_T 61
#define EOS_T 62
#define BB 512
#define SS 1024
#define RPW 16
#define LOG2E 1.4426950408889634f
#define LN2   0.6931471805599453f

typedef float f32x4 __attribute__((ext_vector_type(4)));
typedef int   i32x4 __attribute__((ext_vector_type(4)));
typedef short bf16x8 __attribute__((ext_vector_type(8)));

__device__ __forceinline__ short bf16rne(float v) {
    unsigned u = __float_as_uint(v);
    u += 0x7fffu + ((u >> 16) & 1u);
    return (short)(u >> 16);
}

#define CVTPK(D, LO, HI) asm("v_cvt_pk_bf16_f32 %0, %1, %2" : "=v"(D) : "v"(LO), "v"(HI))
#define SWAP32(X, Y) asm("v_permlane32_swap_b32 %0, %1" : "+v"(X), "+v"(Y))
#define SWAP16(X, Y) asm("v_permlane16_swap_b32 %0, %1" : "+v"(X), "+v"(Y))

__device__ __forceinline__ void gl_lds16(const void* g, void* l) {
    __builtin_amdgcn_global_load_lds((const __attribute__((address_space(1))) void*)g,
                                     (__attribute__((address_space(3))) void*)l, 16, 0, 0);
}

// ---- pass 1: E2 lane-packed bf16 exp(emissions) ----
// thread (t,row,q): writes 16B = [k0:tags 4q+0..3 | k1:tags 16+4q+0..3] at
// (t*32+seg)*2048 + (16q+c)*16, and the k2/k3 16B at +1024. Wave-coalesced 1KB stores.
__global__ __launch_bounds__(256) void exp_pass(const float* __restrict__ em,
                                                char* __restrict__ E2) {
    unsigned g = blockIdx.x * 256 + threadIdx.x;    // < 512*1024*4
    int q = g & 3;
    unsigned rt = g >> 2;
    int row = rt & (BB - 1);
    int t = (int)(rt >> 9);
    const float* p = em + ((size_t)row * SS + t) * NTAG + 4 * q;
    f32x4 a = *(const f32x4*)(p);
    f32x4 b = *(const f32x4*)(p + 16);
    f32x4 cc = *(const f32x4*)(p + 32);
    f32x4 d = *(const f32x4*)(p + 48);
    f32x4 ea, eb, ec, ed;
#pragma unroll
    for (int r = 0; r < 4; ++r) {
        ea[r] = exp2f(a[r] * LOG2E);
        eb[r] = exp2f(b[r] * LOG2E);
        ec[r] = exp2f(cc[r] * LOG2E);
        ed[r] = exp2f(d[r] * LOG2E);
    }
    int w0, w1, w2, w3, w4, w5, w6, w7;
    CVTPK(w0, ea[0], ea[1]); CVTPK(w1, ea[2], ea[3]);
    CVTPK(w2, eb[0], eb[1]); CVTPK(w3, eb[2], eb[3]);
    CVTPK(w4, ec[0], ec[1]); CVTPK(w5, ec[2], ec[3]);
    CVTPK(w6, ed[0], ed[1]); CVTPK(w7, ed[2], ed[3]);
    i32x4 v0 = {w0, w1, w2, w3};
    i32x4 v1 = {w4, w5, w6, w7};
    char* base = E2 + ((size_t)(t * 32 + (row >> 4))) * 2048 + (16 * q + (row & 15)) * 16;
    *(i32x4*)base = v0;
    *(i32x4*)(base + 1024) = v1;
}

// per-row (per c) exact pow2 rescale; cross-q max via permlane swaps (VALU only)
#define RESCALE() do {                                                       \
    f32x4 m4_;                                                               \
    _Pragma("unroll")                                                        \
    for (int r_ = 0; r_ < 4; ++r_)                                           \
        m4_[r_] = fmaxf(fmaxf(x0[r_], x1[r_]), fmaxf(x2[r_], x3[r_]));       \
    float mx_ = fmaxf(fmaxf(m4_[0], m4_[1]), fmaxf(m4_[2], m4_[3]));         \
    float c0_ = mx_, c1_ = mx_;                                              \
    SWAP32(c0_, c1_);                                                        \
    mx_ = fmaxf(mx_, fmaxf(c0_, c1_));                                       \
    float d0_ = mx_, d1_ = mx_;                                              \
    SWAP16(d0_, d1_);                                                        \
    mx_ = fmaxf(mx_, fmaxf(d0_, d1_));                                       \
    int ee_ = ((__float_as_int(mx_) >> 23) & 255) - 127;                     \
    float scl_ = __int_as_float((127 - ee_) << 23);                          \
    x0 *= scl_; x1 *= scl_; x2 *= scl_; x3 *= scl_;                          \
    Mf += (float)ee_;                                                        \
} while (0)

#define PACK_PAIR(XA, XB, RA, RB, LOW, HIGH) do {                            \
    int p0_, p1_;                                                            \
    CVTPK(p0_, (XA)[RA], (XA)[RB]);                                          \
    CVTPK(p1_, (XB)[RA], (XB)[RB]);                                          \
    SWAP32(p0_, p1_);                                                        \
    SWAP16(p0_, p1_);                                                        \
    LOW = p0_; HIGH = p1_;                                                   \
} while (0)

#define PACKB() do {                                                         \
    PACK_PAIR(x0, x1, 0, 1, b0i[0], b0i[2]);                                 \
    PACK_PAIR(x0, x1, 2, 3, b0i[1], b0i[3]);                                 \
    PACK_PAIR(x2, x3, 0, 1, b1i[0], b1i[2]);                                 \
    PACK_PAIR(x2, x3, 2, 3, b1i[1], b1i[3]);                                 \
} while (0)

// one step; CP*/CMI = consume set (ds_read'd last step), QP*/QMI = prefetch set
#define BODY(T, CP0, CP1, CMI, QP0, QP1, QMI) do {                            \
    int tt_ = (T);                                                            \
    { int tg_ = tt_ + 14; tg_ = tg_ > SS - 1 ? SS - 1 : tg_;                  \
      const char* gb_ = E2b + ((size_t)(tg_ * 32 + seg)) * 2048 + lane * 16;  \
      char* lb_ = (char*)Elds + ((tg_ & 15) * 2048);                          \
      gl_lds16(gb_, lb_);                                                     \
      gl_lds16(gb_ + 1024, lb_ + 1024);                                       \
    }                                                                         \
    asm volatile("s_waitcnt vmcnt(26)");                                      \
    { int tn_ = tt_ + 1; tn_ = tn_ > SS - 1 ? SS - 1 : tn_;                   \
      unsigned ea_ = ldsEl + (unsigned)((tn_ & 15) * 2048);                   \
      unsigned ma_ = ldsMc + (unsigned)tn_;                                   \
      asm volatile("ds_read_b128 %0, %2 offset:0\n\t"                         \
                   "ds_read_b128 %1, %2 offset:1024"                          \
                   : "=&v"(QP0), "=&v"(QP1) : "v"(ea_));                      \
      asm volatile("ds_read_u8 %0, %1" : "=&v"(QMI) : "v"(ma_));              \
    }                                                                         \
    bf16x8 B0_, B1_;                                                          \
    __builtin_memcpy(&B0_, &b0i, 16);                                         \
    __builtin_memcpy(&B1_, &b1i, 16);                                         \
    f32x4 d0_ = __builtin_amdgcn_mfma_f32_16x16x32_bf16(af00, B0_, Z4, 0,0,0);\
    f32x4 d1_ = __builtin_amdgcn_mfma_f32_16x16x32_bf16(af10, B0_, Z4, 0,0,0);\
    f32x4 d2_ = __builtin_amdgcn_mfma_f32_16x16x32_bf16(af20, B0_, Z4, 0,0,0);\
    f32x4 d3_ = __builtin_amdgcn_mfma_f32_16x16x32_bf16(af30, B0_, Z4, 0,0,0);\
    d0_ = __builtin_amdgcn_mfma_f32_16x16x32_bf16(af01, B1_, d0_, 0,0,0);     \
    d1_ = __builtin_amdgcn_mfma_f32_16x16x32_bf16(af11, B1_, d1_, 0,0,0);     \
    d2_ = __builtin_amdgcn_mfma_f32_16x16x32_bf16(af21, B1_, d2_, 0,0,0);     \
    d3_ = __builtin_amdgcn_mfma_f32_16x16x32_bf16(af31, B1_, d3_, 0,0,0);     \
    asm volatile("s_waitcnt lgkmcnt(3)");                                     \
    __builtin_amdgcn_sched_barrier(0);                                        \
    f32x4 f0_, f1_, f2_, f3_;                                                 \
    f0_[0] = __int_as_float((CP0)[0] << 16);                                  \
    f0_[1] = __int_as_float((CP0)[0] & (int)0xffff0000);                      \
    f0_[2] = __int_as_float((CP0)[1] << 16);                                  \
    f0_[3] = __int_as_float((CP0)[1] & (int)0xffff0000);                      \
    f1_[0] = __int_as_float((CP0)[2] << 16);                                  \
    f1_[1] = __int_as_float((CP0)[2] & (int)0xffff0000);                      \
    f1_[2] = __int_as_float((CP0)[3] << 16);                                  \
    f1_[3] = __int_as_float((CP0)[3] & (int)0xffff0000);                      \
    f2_[0] = __int_as_float((CP1)[0] << 16);                                  \
    f2_[1] = __int_as_float((CP1)[0] & (int)0xffff0000);                      \
    f2_[2] = __int_as_float((CP1)[1] << 16);                                  \
    f2_[3] = __int_as_float((CP1)[1] & (int)0xffff0000);                      \
    f3_[0] = __int_as_float((CP1)[2] << 16);                                  \
    f3_[1] = __int_as_float((CP1)[2] & (int)0xffff0000);                      \
    f3_[2] = __int_as_float((CP1)[3] << 16);                                  \
    f3_[3] = __int_as_float((CP1)[3] & (int)0xffff0000);                      \
    int mki_ = (CMI);                                                         \
    if (__all(mki_ != 0)) {                                                   \
        x0 = d0_ * f0_; x1 = d1_ * f1_; x2 = d2_ * f2_; x3 = d3_ * f3_;       \
    } else {                                                                  \
        bool lv_ = (mki_ != 0);                                               \
        _Pragma("unroll")                                                     \
        for (int r_ = 0; r_ < 4; ++r_) {                                      \
            x0[r_] = lv_ ? d0_[r_] * f0_[r_] : x0[r_];                        \
            x1[r_] = lv_ ? d1_[r_] * f1_[r_] : x1[r_];                        \
            x2[r_] = lv_ ? d2_[r_] * f2_[r_] : x2[r_];                        \
            x3[r_] = lv_ ? d3_[r_] * f3_[r_] : x3[r_];                        \
        }                                                                     \
    }                                                                         \
    if ((tt_ & 7) == 0) RESCALE();                                            \
    PACKB();                                                                  \
} while (0)

__global__ __launch_bounds__(64, 1) void crf_scan(
    const float* __restrict__ emissions,  // [B,S,64]
    const int*   __restrict__ tags,       // [B,S]
    const float* __restrict__ mask,       // [B,S]
    const float* __restrict__ trans,      // [64,64]
    const char*  __restrict__ E2b,        // lane-packed bf16 exp(em)
    float* __restrict__ out)              // [1]
{
    const int lane = threadIdx.x;
    const int c = lane & 15;              // batch row within wave
    const int q = lane >> 4;              // k/m lane-group
    const int seg = blockIdx.x;
    const int row = seg * RPW + c;

    __shared__ __align__(16) char  Elds[16 * 2048];       // 32KB E ring
    __shared__ __align__(4)  char  MBlds[16 * 1028 + 4];  // mask bytes, padded stride

    // ---- A-frags straight from global trans (L2-resident, 16KB) ----
    bf16x8 af00, af01, af10, af11, af20, af21, af30, af31;
#pragma unroll
    for (int e = 0; e < 8; ++e) {
        af00[e] = bf16rne(exp2f(trans[( 0 + 8*q + e)*NTAG + ( 0 + c)] * LOG2E));
        af01[e] = bf16rne(exp2f(trans[(32 + 8*q + e)*NTAG + ( 0 + c)] * LOG2E));
        af10[e] = bf16rne(exp2f(trans[( 0 + 8*q + e)*NTAG + (16 + c)] * LOG2E));
        af11[e] = bf16rne(exp2f(trans[(32 + 8*q + e)*NTAG + (16 + c)] * LOG2E));
        af20[e] = bf16rne(exp2f(trans[( 0 + 8*q + e)*NTAG + (32 + c)] * LOG2E));
        af21[e] = bf16rne(exp2f(trans[(32 + 8*q + e)*NTAG + (32 + c)] * LOG2E));
        af30[e] = bf16rne(exp2f(trans[( 0 + 8*q + e)*NTAG + (48 + c)] * LOG2E));
        af31[e] = bf16rne(exp2f(trans[(32 + 8*q + e)*NTAG + (48 + c)] * LOG2E));
    }

    const float* emb = emissions + (size_t)row * SS * NTAG;
    const int*   tgb = tags + (size_t)row * SS;
    const float* mkb = mask + (size_t)row * SS;

    // ---- stage mask bytes to LDS (block rows contiguous) ----
    const float* mseg = mask + (size_t)seg * RPW * SS;
#pragma unroll 4
    for (int it = 0; it < 64; ++it) {
        int e4 = it * 256 + lane * 4;
        f32x4 mv = *(const f32x4*)(mseg + e4);
        unsigned pk = (mv[0] != 0.f ? 1u : 0u) | (mv[1] != 0.f ? 0x100u : 0u) |
                      (mv[2] != 0.f ? 0x10000u : 0u) | (mv[3] != 0.f ? 0x1000000u : 0u);
        *(unsigned*)(&MBlds[(e4 >> 10) * 1028 + (e4 & 1023)]) = pk;
    }

    // ---- gold-path score + msum ----
    float scp = 0.f, msp = 0.f;
#pragma unroll 4
    for (int k = 0; k < SS / 4; ++k) {
        int t = 4 * k + q;
        int tg = tgb[t];
        float m = mkb[t];
        msp += m;
        float e = emb[t * NTAG + tg];
        if (t == 0) {
            scp += trans[SOS_T * NTAG + tg] + e;
        } else {
            int tp = tgb[t - 1];
            scp += m * (e + trans[tp * NTAG + tg]);
        }
    }
    scp += __shfl_xor(scp, 16); scp += __shfl_xor(scp, 32);
    msp += __shfl_xor(msp, 16); msp += __shfl_xor(msp, 32);
    int last_idx = (int)(msp + 0.5f) - 1;
    int last_tag = tgb[last_idx];
    float sc_row = scp + trans[last_tag * NTAG + EOS_T];

    // ---- X init at t=0 ----
    f32x4 x0, x1, x2, x3;
    float Mf = 0.f;
#pragma unroll
    for (int r = 0; r < 4; ++r) {
        int tg0 =  0 + 4*q + r, tg1 = 16 + 4*q + r;
        int tg2 = 32 + 4*q + r, tg3 = 48 + 4*q + r;
        x0[r] = exp2f((trans[SOS_T*NTAG + tg0] + emb[tg0]) * LOG2E);
        x1[r] = exp2f((trans[SOS_T*NTAG + tg1] + emb[tg1]) * LOG2E);
        x2[r] = exp2f((trans[SOS_T*NTAG + tg2] + emb[tg2]) * LOG2E);
        x3[r] = exp2f((trans[SOS_T*NTAG + tg3] + emb[tg3]) * LOG2E);
    }
    RESCALE();
    i32x4 b0i, b1i;
    PACKB();
    const f32x4 Z4 = {0.f, 0.f, 0.f, 0.f};

    const unsigned ldsEl = (unsigned)(uintptr_t)&Elds[0] + (unsigned)lane * 16;
    const unsigned ldsMc = (unsigned)(uintptr_t)&MBlds[0] + (unsigned)c * 1028;

    // ---- fence prologue memory, warm the ring (steps 1..14), first ds_read ----
    asm volatile("s_waitcnt vmcnt(0) lgkmcnt(0)" ::: "memory");
#pragma unroll
    for (int w = 1; w <= 14; ++w) {
        const char* gb = E2b + ((size_t)(w * 32 + seg)) * 2048 + lane * 16;
        char* lb = (char*)Elds + ((w & 15) * 2048);
        gl_lds16(gb, lb);
        gl_lds16(gb + 1024, lb + 1024);
    }
    i32x4 pA0 = {0,0,0,0}, pA1 = pA0, pB0 = pA0, pB1 = pA0;
    int mAi = 1, mBi = 1;
    asm volatile("s_waitcnt vmcnt(26)");
    {
        unsigned ea = ldsEl + 1 * 2048;
        unsigned ma = ldsMc + 1;
        asm volatile("ds_read_b128 %0, %2 offset:0\n\t"
                     "ds_read_b128 %1, %2 offset:1024"
                     : "=&v"(pB0), "=&v"(pB1) : "v"(ea));
        asm volatile("ds_read_u8 %0, %1" : "=&v"(mBi) : "v"(ma));
    }

    // ---- main recursion: t = 1..1023 ----
#pragma unroll 1
    for (int t = 1; t <= SS - 3; t += 2) {
        BODY(t,     pB0, pB1, mBi, pA0, pA1, mAi);
        BODY(t + 1, pA0, pA1, mAi, pB0, pB1, mBi);
    }
    BODY(SS - 1, pB0, pB1, mBi, pA0, pA1, mAi);

    // ---- finalize ----
    float v = 0.f;
#pragma unroll
    for (int r = 0; r < 4; ++r) {
        v += x0[r] * exp2f(trans[( 0 + 4*q + r) * NTAG + EOS_T] * LOG2E);
        v += x1[r] * exp2f(trans[(16 + 4*q + r) * NTAG + EOS_T] * LOG2E);
        v += x2[r] * exp2f(trans[(32 + 4*q + r) * NTAG + EOS_T] * LOG2E);
        v += x3[r] * exp2f(trans[(48 + 4*q + r) * NTAG + EOS_T] * LOG2E);
    }
    v += __shfl_xor(v, 16); v += __shfl_xor(v, 32);
    float logz = (log2f(v) + Mf) * LN2;
    float nll = logz - sc_row;      // replicated 4x across q groups
#pragma unroll
    for (int o = 1; o < 64; o <<= 1) nll += __shfl_xor(nll, o);
    if (lane == 0) atomicAdd(out, nll * 0.25f);
}

extern "C" void kernel_launch(void* const* d_in, const int* in_sizes, int n_in,
                              void* d_out, int out_size, void* d_ws, size_t ws_size,
                              hipStream_t stream) {
    const float* emissions = (const float*)d_in[0];
    const int*   tags      = (const int*)d_in[1];
    const float* mask      = (const float*)d_in[2];
    const float* trans     = (const float*)d_in[3];
    float* out = (float*)d_out;
    char* E2 = (char*)d_ws;   // 64MB, proven available in round 9

    hipMemsetAsync(out, 0, sizeof(float), stream);
    exp_pass<<<dim3(BB * SS * 4 / 256), dim3(256), 0, stream>>>(emissions, E2);
    crf_scan<<<dim3(BB / RPW), dim3(64), 0, stream>>>(
        emissions, tags, mask, trans, E2, out);
}

// Round 11
// 376.796 us; speedup vs baseline: 1.0763x; 1.0763x over previous
//
#include <hip/hip_runtime.h>

#define NTAG 64
#define SOS_T 61
#define EOS_T 62
#define BB 512
#define SS 1024
#define RPW 16
#define LOG2E 1.4426950408889634f
#define LN2   0.6931471805599453f

typedef float f32x4 __attribute__((ext_vector_type(4)));
typedef int   i32x4 __attribute__((ext_vector_type(4)));
typedef short bf16x8 __attribute__((ext_vector_type(8)));

__device__ __forceinline__ short bf16rne(float v) {
    unsigned u = __float_as_uint(v);
    u += 0x7fffu + ((u >> 16) & 1u);
    return (short)(u >> 16);
}

#define CVTPK(D, LO, HI) asm("v_cvt_pk_bf16_f32 %0, %1, %2" : "=v"(D) : "v"(LO), "v"(HI))
#define SWAP32(X, Y) asm("v_permlane32_swap_b32 %0, %1" : "+v"(X), "+v"(Y))
#define SWAP16(X, Y) asm("v_permlane16_swap_b32 %0, %1" : "+v"(X), "+v"(Y))

// ---- pass 1: E2 lane-packed bf16 exp(emissions) (verified r10) ----
__global__ __launch_bounds__(256) void exp_pass(const float* __restrict__ em,
                                                char* __restrict__ E2) {
    unsigned g = blockIdx.x * 256 + threadIdx.x;    // < 512*1024*4
    int q = g & 3;
    unsigned rt = g >> 2;
    int row = rt & (BB - 1);
    int t = (int)(rt >> 9);
    const float* p = em + ((size_t)row * SS + t) * NTAG + 4 * q;
    f32x4 a = *(const f32x4*)(p);
    f32x4 b = *(const f32x4*)(p + 16);
    f32x4 cc = *(const f32x4*)(p + 32);
    f32x4 d = *(const f32x4*)(p + 48);
    f32x4 ea, eb, ec, ed;
#pragma unroll
    for (int r = 0; r < 4; ++r) {
        ea[r] = exp2f(a[r] * LOG2E);
        eb[r] = exp2f(b[r] * LOG2E);
        ec[r] = exp2f(cc[r] * LOG2E);
        ed[r] = exp2f(d[r] * LOG2E);
    }
    int w0, w1, w2, w3, w4, w5, w6, w7;
    CVTPK(w0, ea[0], ea[1]); CVTPK(w1, ea[2], ea[3]);
    CVTPK(w2, eb[0], eb[1]); CVTPK(w3, eb[2], eb[3]);
    CVTPK(w4, ec[0], ec[1]); CVTPK(w5, ec[2], ec[3]);
    CVTPK(w6, ed[0], ed[1]); CVTPK(w7, ed[2], ed[3]);
    i32x4 v0 = {w0, w1, w2, w3};
    i32x4 v1 = {w4, w5, w6, w7};
    char* base = E2 + ((size_t)(t * 32 + (row >> 4))) * 2048 + (16 * q + (row & 15)) * 16;
    *(i32x4*)base = v0;
    *(i32x4*)(base + 1024) = v1;
}

// per-row (per c) exact pow2 rescale; cross-q max via permlane swaps (VALU only)
#define RESCALE() do {                                                       \
    f32x4 m4_;                                                               \
    _Pragma("unroll")                                                        \
    for (int r_ = 0; r_ < 4; ++r_)                                           \
        m4_[r_] = fmaxf(fmaxf(x0[r_], x1[r_]), fmaxf(x2[r_], x3[r_]));       \
    float mx_ = fmaxf(fmaxf(m4_[0], m4_[1]), fmaxf(m4_[2], m4_[3]));         \
    float c0_ = mx_, c1_ = mx_;                                              \
    SWAP32(c0_, c1_);                                                        \
    mx_ = fmaxf(mx_, fmaxf(c0_, c1_));                                       \
    float d0_ = mx_, d1_ = mx_;                                              \
    SWAP16(d0_, d1_);                                                        \
    mx_ = fmaxf(mx_, fmaxf(d0_, d1_));                                       \
    int ee_ = ((__float_as_int(mx_) >> 23) & 255) - 127;                     \
    float scl_ = __int_as_float((127 - ee_) << 23);                          \
    x0 *= scl_; x1 *= scl_; x2 *= scl_; x3 *= scl_;                          \
    Mf += (float)ee_;                                                        \
} while (0)

#define PACK_PAIR(XA, XB, RA, RB, LOW, HIGH) do {                            \
    int p0_, p1_;                                                            \
    CVTPK(p0_, (XA)[RA], (XA)[RB]);                                          \
    CVTPK(p1_, (XB)[RA], (XB)[RB]);                                          \
    SWAP32(p0_, p1_);                                                        \
    SWAP16(p0_, p1_);                                                        \
    LOW = p0_; HIGH = p1_;                                                   \
} while (0)

#define PACKB() do {                                                         \
    PACK_PAIR(x0, x1, 0, 1, b0i[0], b0i[2]);                                 \
    PACK_PAIR(x0, x1, 2, 3, b0i[1], b0i[3]);                                 \
    PACK_PAIR(x2, x3, 0, 1, b1i[0], b1i[2]);                                 \
    PACK_PAIR(x2, x3, 2, 3, b1i[1], b1i[3]);                                 \
} while (0)

// One step t in ring slot K. WN = vmcnt wait count (stringized literal),
// ISS = issue prefetch for t+8 into slot K, RESC = pow2 rescale.
// Order: MFMA (prev-step B, fills the wait shadow) -> wait vmcnt ->
// sched_barrier -> unpack slot K -> issue t+8 -> select -> pack.
#define BODY(T, K, WN, ISS, RESC) do {                                        \
    int tt_ = (T);                                                            \
    bf16x8 B0_, B1_;                                                          \
    __builtin_memcpy(&B0_, &b0i, 16);                                         \
    __builtin_memcpy(&B1_, &b1i, 16);                                         \
    f32x4 d0_ = __builtin_amdgcn_mfma_f32_16x16x32_bf16(af00, B0_, Z4, 0,0,0);\
    f32x4 d1_ = __builtin_amdgcn_mfma_f32_16x16x32_bf16(af10, B0_, Z4, 0,0,0);\
    f32x4 d2_ = __builtin_amdgcn_mfma_f32_16x16x32_bf16(af20, B0_, Z4, 0,0,0);\
    f32x4 d3_ = __builtin_amdgcn_mfma_f32_16x16x32_bf16(af30, B0_, Z4, 0,0,0);\
    d0_ = __builtin_amdgcn_mfma_f32_16x16x32_bf16(af01, B1_, d0_, 0,0,0);     \
    d1_ = __builtin_amdgcn_mfma_f32_16x16x32_bf16(af11, B1_, d1_, 0,0,0);     \
    d2_ = __builtin_amdgcn_mfma_f32_16x16x32_bf16(af21, B1_, d2_, 0,0,0);     \
    d3_ = __builtin_amdgcn_mfma_f32_16x16x32_bf16(af31, B1_, d3_, 0,0,0);     \
    asm volatile("s_waitcnt vmcnt(" #WN ")");                                 \
    __builtin_amdgcn_sched_barrier(0);                                        \
    f32x4 f0_, f1_, f2_, f3_;                                                 \
    f0_[0] = __int_as_float(er[K][0][0] << 16);                               \
    f0_[1] = __int_as_float(er[K][0][0] & (int)0xffff0000);                   \
    f0_[2] = __int_as_float(er[K][0][1] << 16);                               \
    f0_[3] = __int_as_float(er[K][0][1] & (int)0xffff0000);                   \
    f1_[0] = __int_as_float(er[K][0][2] << 16);                               \
    f1_[1] = __int_as_float(er[K][0][2] & (int)0xffff0000);                   \
    f1_[2] = __int_as_float(er[K][0][3] << 16);                               \
    f1_[3] = __int_as_float(er[K][0][3] & (int)0xffff0000);                   \
    f2_[0] = __int_as_float(er[K][1][0] << 16);                               \
    f2_[1] = __int_as_float(er[K][1][0] & (int)0xffff0000);                   \
    f2_[2] = __int_as_float(er[K][1][1] << 16);                               \
    f2_[3] = __int_as_float(er[K][1][1] & (int)0xffff0000);                   \
    f3_[0] = __int_as_float(er[K][1][2] << 16);                               \
    f3_[1] = __int_as_float(er[K][1][2] & (int)0xffff0000);                   \
    f3_[2] = __int_as_float(er[K][1][3] << 16);                               \
    f3_[3] = __int_as_float(er[K][1][3] & (int)0xffff0000);                   \
    float mkf_ = mrf[K];                                                      \
    if (ISS) {                                                                \
        int tg_ = tt_ + 8; tg_ = tg_ > SS - 1 ? SS - 1 : tg_;                 \
        const char* gb_ = E2b + ((size_t)(tg_ * 32 + seg)) * 2048             \
                          + (size_t)lane * 16;                                \
        const float* mp_ = mkb + tg_;                                         \
        asm volatile("global_load_dwordx4 %0, %1, off"                        \
                     : "=&v"(er[K][0]) : "v"(gb_));                           \
        asm volatile("global_load_dwordx4 %0, %1, off"                        \
                     : "=&v"(er[K][1]) : "v"(gb_ + 1024));                    \
        asm volatile("global_load_dword %0, %1, off"                          \
                     : "=&v"(mrf[K]) : "v"(mp_));                             \
    }                                                                         \
    if (__all(mkf_ != 0.0f)) {                                                \
        x0 = d0_ * f0_; x1 = d1_ * f1_; x2 = d2_ * f2_; x3 = d3_ * f3_;       \
    } else {                                                                  \
        bool lv_ = (mkf_ != 0.0f);                                            \
        _Pragma("unroll")                                                     \
        for (int r_ = 0; r_ < 4; ++r_) {                                      \
            x0[r_] = lv_ ? d0_[r_] * f0_[r_] : x0[r_];                        \
            x1[r_] = lv_ ? d1_[r_] * f1_[r_] : x1[r_];                        \
            x2[r_] = lv_ ? d2_[r_] * f2_[r_] : x2[r_];                        \
            x3[r_] = lv_ ? d3_[r_] * f3_[r_] : x3[r_];                        \
        }                                                                     \
    }                                                                         \
    if (RESC) RESCALE();                                                      \
    PACKB();                                                                  \
} while (0)

__global__ __launch_bounds__(64, 1) void crf_scan(
    const float* __restrict__ emissions,  // [B,S,64]
    const int*   __restrict__ tags,       // [B,S]
    const float* __restrict__ mask,       // [B,S]
    const float* __restrict__ trans,      // [64,64]
    const char*  __restrict__ E2b,        // lane-packed bf16 exp(em)
    float* __restrict__ out)              // [1]
{
    const int lane = threadIdx.x;
    const int c = lane & 15;              // batch row within wave
    const int q = lane >> 4;              // k/m lane-group
    const int seg = blockIdx.x;
    const int row = seg * RPW + c;

    // ---- A-frags straight from global trans (L2-resident, 16KB) ----
    bf16x8 af00, af01, af10, af11, af20, af21, af30, af31;
#pragma unroll
    for (int e = 0; e < 8; ++e) {
        af00[e] = bf16rne(exp2f(trans[( 0 + 8*q + e)*NTAG + ( 0 + c)] * LOG2E));
        af01[e] = bf16rne(exp2f(trans[(32 + 8*q + e)*NTAG + ( 0 + c)] * LOG2E));
        af10[e] = bf16rne(exp2f(trans[( 0 + 8*q + e)*NTAG + (16 + c)] * LOG2E));
        af11[e] = bf16rne(exp2f(trans[(32 + 8*q + e)*NTAG + (16 + c)] * LOG2E));
        af20[e] = bf16rne(exp2f(trans[( 0 + 8*q + e)*NTAG + (32 + c)] * LOG2E));
        af21[e] = bf16rne(exp2f(trans[(32 + 8*q + e)*NTAG + (32 + c)] * LOG2E));
        af30[e] = bf16rne(exp2f(trans[( 0 + 8*q + e)*NTAG + (48 + c)] * LOG2E));
        af31[e] = bf16rne(exp2f(trans[(32 + 8*q + e)*NTAG + (48 + c)] * LOG2E));
    }

    const float* emb = emissions + (size_t)row * SS * NTAG;
    const int*   tgb = tags + (size_t)row * SS;
    const float* mkb = mask + (size_t)row * SS;

    // ---- gold-path score + msum (prologue; drained before the ring) ----
    float scp = 0.f, msp = 0.f;
#pragma unroll 4
    for (int k = 0; k < SS / 4; ++k) {
        int t = 4 * k + q;
        int tg = tgb[t];
        float m = mkb[t];
        msp += m;
        float e = emb[t * NTAG + tg];
        if (t == 0) {
            scp += trans[SOS_T * NTAG + tg] + e;
        } else {
            int tp = tgb[t - 1];
            scp += m * (e + trans[tp * NTAG + tg]);
        }
    }
    scp += __shfl_xor(scp, 16); scp += __shfl_xor(scp, 32);
    msp += __shfl_xor(msp, 16); msp += __shfl_xor(msp, 32);
    int last_idx = (int)(msp + 0.5f) - 1;
    int last_tag = tgb[last_idx];
    float sc_row = scp + trans[last_tag * NTAG + EOS_T];

    // ---- finalize constants hoisted (no C loads after the fence) ----
    f32x4 te0, te1, te2, te3;
#pragma unroll
    for (int r = 0; r < 4; ++r) {
        te0[r] = exp2f(trans[( 0 + 4*q + r) * NTAG + EOS_T] * LOG2E);
        te1[r] = exp2f(trans[(16 + 4*q + r) * NTAG + EOS_T] * LOG2E);
        te2[r] = exp2f(trans[(32 + 4*q + r) * NTAG + EOS_T] * LOG2E);
        te3[r] = exp2f(trans[(48 + 4*q + r) * NTAG + EOS_T] * LOG2E);
    }

    // ---- X init at t=0 ----
    f32x4 x0, x1, x2, x3;
    float Mf = 0.f;
#pragma unroll
    for (int r = 0; r < 4; ++r) {
        int tg0 =  0 + 4*q + r, tg1 = 16 + 4*q + r;
        int tg2 = 32 + 4*q + r, tg3 = 48 + 4*q + r;
        x0[r] = exp2f((trans[SOS_T*NTAG + tg0] + emb[tg0]) * LOG2E);
        x1[r] = exp2f((trans[SOS_T*NTAG + tg1] + emb[tg1]) * LOG2E);
        x2[r] = exp2f((trans[SOS_T*NTAG + tg2] + emb[tg2]) * LOG2E);
        x3[r] = exp2f((trans[SOS_T*NTAG + tg3] + emb[tg3]) * LOG2E);
    }
    RESCALE();
    i32x4 b0i, b1i;
    PACKB();
    const f32x4 Z4 = {0.f, 0.f, 0.f, 0.f};

    // ---- register ring: 8 slots x (2 x i32x4 E + 1 float mask) ----
    i32x4 er[8][2];
    float mrf[8];

    // fence ALL prologue memory so in-loop vmcnt counting is exact
    asm volatile("s_waitcnt vmcnt(0) lgkmcnt(0)" ::: "memory");

    // warm-up: issue steps 1..8 into slots 0..7 (24 loads, in order)
#pragma unroll
    for (int w = 0; w < 8; ++w) {
        int tg = 1 + w;
        const char* gb = E2b + ((size_t)(tg * 32 + seg)) * 2048 + (size_t)lane * 16;
        const float* mp = mkb + tg;
        asm volatile("global_load_dwordx4 %0, %1, off" : "=&v"(er[w][0]) : "v"(gb));
        asm volatile("global_load_dwordx4 %0, %1, off" : "=&v"(er[w][1]) : "v"(gb + 1024));
        asm volatile("global_load_dword %0, %1, off" : "=&v"(mrf[w]) : "v"(mp));
    }

    // ---- main recursion: t = 1..1016 (127 x 8), then 7-step tail ----
#pragma unroll 1
    for (int tb = 1; tb <= SS - 15; tb += 8) {
        BODY(tb + 0, 0, 21, 1, 0);
        BODY(tb + 1, 1, 21, 1, 0);
        BODY(tb + 2, 2, 21, 1, 0);
        BODY(tb + 3, 3, 21, 1, 0);
        BODY(tb + 4, 4, 21, 1, 0);
        BODY(tb + 5, 5, 21, 1, 0);
        BODY(tb + 6, 6, 21, 1, 0);
        BODY(tb + 7, 7, 21, 1, 1);
    }
    BODY(SS - 7, 0, 21, 0, 0);
    BODY(SS - 6, 1, 18, 0, 0);
    BODY(SS - 5, 2, 15, 0, 0);
    BODY(SS - 4, 3, 12, 0, 0);
    BODY(SS - 3, 4,  9, 0, 0);
    BODY(SS - 2, 5,  6, 0, 0);
    BODY(SS - 1, 6,  3, 0, 0);
    asm volatile("s_waitcnt vmcnt(0)");

    // ---- finalize: log_z[c] = (log2(sum_tag X[tag][c]*expT[tag][EOS]) + Mf)*ln2 ----
    float v = 0.f;
#pragma unroll
    for (int r = 0; r < 4; ++r) {
        v += x0[r] * te0[r];
        v += x1[r] * te1[r];
        v += x2[r] * te2[r];
        v += x3[r] * te3[r];
    }
    v += __shfl_xor(v, 16); v += __shfl_xor(v, 32);
    float logz = (log2f(v) + Mf) * LN2;
    float nll = logz - sc_row;      // replicated 4x across q groups
#pragma unroll
    for (int o = 1; o < 64; o <<= 1) nll += __shfl_xor(nll, o);
    if (lane == 0) atomicAdd(out, nll * 0.25f);
}

extern "C" void kernel_launch(void* const* d_in, const int* in_sizes, int n_in,
                              void* d_out, int out_size, void* d_ws, size_t ws_size,
                              hipStream_t stream) {
    const float* emissions = (const float*)d_in[0];
    const int*   tags      = (const int*)d_in[1];
    const float* mask      = (const float*)d_in[2];
    const float* trans     = (const float*)d_in[3];
    float* out = (float*)d_out;
    char* E2 = (char*)d_ws;   // 64MB workspace (proven available)

    hipMemsetAsync(out, 0, sizeof(float), stream);
    exp_pass<<<dim3(BB * SS * 4 / 256), dim3(256), 0, stream>>>(emissions, E2);
    crf_scan<<<dim3(BB / RPW), dim3(64), 0, stream>>>(
        emissions, tags, mask, trans, E2, out);
}